// Round 8
// baseline (403.991 us; speedup 1.0000x reference)
//
#include <hip/hip_runtime.h>
#include <hip/hip_bf16.h>

// CausalSelfAttention: B=4 T=2048 C=1024 H=16 D=64
// ws layout (bytes):
//   xb   @ 0         : x as bf16           [8192][1024]   16 MB
//   wat  @ 16777216  : w_attn^T bf16       [3072][1024]    6 MB
//   wpt  @ 23068672  : w_proj^T bf16       [1024][1024]    2 MB
//   Qb   @ 25165824  : Q bf16 (pre-scaled by 0.125*log2e) [B,H,T,D] 16 MB
//   Kb   @ 41943040  : K bf16  [B,H,T,D]                  16 MB
//   Vtb  @ 58720256  : V^T bf16 [B,H,D,T]  (written directly by gemm_qkv)
//   Ob   @ 75497472  : attn out bf16 [8192][1024]         16 MB
//
// R19: flash_attn rewritten BARRIER-FREE. R18 post-mortem: all five gemm
// schedule variants land at 600-640 TF (theories falsified: barriers/phase
// density/co-residency); the biggest kernel is actually flash_attn
// (~105-115 us by subtraction, ~300 TF), with a 4x stall dilation from the
// per-iter __syncthreads lockstep. K/V per head = 256 KB = L2/L3-resident
// (m169: staging L2-fit data is pure overhead), so: no LDS, no barriers —
// each wave reads K-frags (b128) and V^T-frags (b64) directly from global,
// loops its own nkt = ((qbase+31)>>6)+1 (same computed-tile set as before).
// Grid 1024 (one qtile/block, long tiles first); zero LDS -> 4-5 blocks/CU
// of independent waves hide L2 latency; L1 serves intra-block K/V reuse.
// GEMMs unchanged from R18 (dbuf 128x128).

typedef float f32x4 __attribute__((ext_vector_type(4)));
typedef float f32x16 __attribute__((ext_vector_type(16)));
typedef short short8 __attribute__((ext_vector_type(8)));
typedef short short4v __attribute__((ext_vector_type(4)));

__device__ __forceinline__ short f2bf(float f) {
  union { __hip_bfloat16 h; short s; } u;
  u.h = __float2bfloat16(f);
  return u.s;
}

__device__ __forceinline__ void gl_lds16(const void* g, void* l) {
  __builtin_amdgcn_global_load_lds(
      (const __attribute__((address_space(1))) void*)g,
      (__attribute__((address_space(3))) void*)l, 16, 0, 0);
}

// ---------------- fused prep: x cvt + w_attn^T + w_proj^T -------------------
__global__ void prep(const float* __restrict__ x, const float* __restrict__ wa,
                     const float* __restrict__ wp, short* __restrict__ xb,
                     short* __restrict__ wat, short* __restrict__ wpt) {
  const int bid = blockIdx.x, tid = threadIdx.x;
  if (bid < 8192) {
    int i = (bid * 256 + tid) * 4;
    float4 v = *(const float4*)(x + i);
    short4v o;
    o[0] = f2bf(v.x); o[1] = f2bf(v.y); o[2] = f2bf(v.z); o[3] = f2bf(v.w);
    *(short4v*)(xb + i) = o;
    return;
  }
  __shared__ float tile[32][33];
  const float* in;
  short* out;
  int N, bx, by;
  if (bid < 11264) {
    int t = bid - 8192;
    in = wa; out = wat; N = 3072; bx = t % 96; by = t / 96;
  } else {
    int t = bid - 11264;
    in = wp; out = wpt; N = 1024; bx = t & 31; by = t >> 5;
  }
  int tx = tid & 31, ty = tid >> 5;  // 32 x 8
  int x0 = bx * 32, y0 = by * 32;
#pragma unroll
  for (int i = 0; i < 32; i += 8)
    tile[ty + i][tx] = in[(size_t)(y0 + ty + i) * N + x0 + tx];
  __syncthreads();
#pragma unroll
  for (int i = 0; i < 32; i += 8)
    out[(size_t)(x0 + ty + i) * 1024 + y0 + tx] = f2bf(tile[tx][ty + i]);
}

// ------ GEMM core: 128x128, BK=32, 4 waves, DBUF LDS, 1 barrier/kt ---------
#define GEMM_BODY(A_, Bt_)                                                        \
  __shared__ __align__(16) short As[2][128 * 32];                                 \
  __shared__ __align__(16) short Bs[2][128 * 32];                                 \
  const int tid = threadIdx.x;                                                    \
  const int wv = tid >> 6;                                                        \
  const int wr = wv >> 1, wc = wv & 1;                                            \
  const int col = tid & 31, khalf = (tid >> 5) & 1;                               \
  const int m0 = blockIdx.y * 128, n0 = blockIdx.x * 128;                         \
  const int cc0 = tid, cc1 = tid + 256;                                           \
  const int row0 = cc0 >> 2, part0 = ((cc0 & 3) - ((cc0 >> 3) & 3)) & 3;          \
  const int row1 = cc1 >> 2, part1 = ((cc1 & 3) - ((cc1 >> 3) & 3)) & 3;          \
  const size_t ga0 = (size_t)(m0 + row0) * 1024 + part0 * 8;                      \
  const size_t ga1 = (size_t)(m0 + row1) * 1024 + part1 * 8;                      \
  const size_t gb0 = (size_t)(n0 + row0) * 1024 + part0 * 8;                      \
  const size_t gb1 = (size_t)(n0 + row1) * 1024 + part1 * 8;                      \
  f32x16 acc[2][2];                                                               \
  _Pragma("unroll") for (int i = 0; i < 2; ++i)                                   \
      _Pragma("unroll") for (int j = 0; j < 2; ++j)                               \
          acc[i][j] = (f32x16)(0.f);                                              \
  gl_lds16(A_ + ga0, (char*)As[0] + cc0 * 16);                                    \
  gl_lds16(A_ + ga1, (char*)As[0] + cc1 * 16);                                    \
  gl_lds16(Bt_ + gb0, (char*)Bs[0] + cc0 * 16);                                   \
  gl_lds16(Bt_ + gb1, (char*)Bs[0] + cc1 * 16);                                   \
  __syncthreads();                                                                \
  for (int kt = 0; kt < 32; ++kt) {                                               \
    if (kt + 1 < 32) {                                                            \
      const int k0 = (kt + 1) * 32;                                               \
      char* Ad = (char*)As[(kt + 1) & 1];                                         \
      char* Bd = (char*)Bs[(kt + 1) & 1];                                         \
      gl_lds16(A_ + ga0 + k0, Ad + cc0 * 16);                                     \
      gl_lds16(A_ + ga1 + k0, Ad + cc1 * 16);                                     \
      gl_lds16(Bt_ + gb0 + k0, Bd + cc0 * 16);                                    \
      gl_lds16(Bt_ + gb1 + k0, Bd + cc1 * 16);                                    \
    }                                                                             \
    const short* Ac = As[kt & 1];                                                 \
    const short* Bc = Bs[kt & 1];                                                 \
    short8 af[2][2], bf[2][2];                                                    \
    _Pragma("unroll") for (int i = 0; i < 2; ++i)                                 \
        _Pragma("unroll") for (int s = 0; s < 2; ++s) {                           \
          int pa = s * 2 + khalf;                                                 \
          int ra = wr * 64 + i * 32 + col;                                        \
          int rb = wc * 64 + i * 32 + col;                                        \
          af[i][s] = *(const short8*)&Ac[(ra * 4 + ((pa + (ra >> 1)) & 3)) * 8];  \
          bf[i][s] = *(const short8*)&Bc[(rb * 4 + ((pa + (rb >> 1)) & 3)) * 8];  \
        }                                                                         \
    _Pragma("unroll") for (int s = 0; s < 2; ++s)                                 \
        _Pragma("unroll") for (int i = 0; i < 2; ++i)                             \
            _Pragma("unroll") for (int j = 0; j < 2; ++j)                         \
                acc[i][j] = __builtin_amdgcn_mfma_f32_32x32x16_bf16(              \
                    af[i][s], bf[j][s], acc[i][j], 0, 0, 0);                      \
    __syncthreads();                                                              \
  }

// QKV GEMM. Q pre-scaled by 0.125*log2(e). V written directly transposed to
// Vtb [bh][d][t]: C/D reg-groups (a&3) are 4 consecutive m=t -> b64 stores.
__global__ __launch_bounds__(256, 2) void gemm_qkv(
    const short* __restrict__ A, const short* __restrict__ Bt,
    const float* __restrict__ bias, short* __restrict__ Qb,
    short* __restrict__ Kb, short* __restrict__ Vtb) {
  GEMM_BODY(A, Bt)
  const int rhalf = khalf * 4;
#pragma unroll
  for (int i = 0; i < 2; ++i) {
#pragma unroll
    for (int j = 0; j < 2; ++j) {
      int n = n0 + wc * 64 + j * 32 + col;
      int n2 = n & 1023;
      int hh = n2 >> 6, d = n2 & 63;
      float bv = bias[n];
      int mb = m0 + wr * 64 + i * 32 + rhalf;
      int bb = mb >> 11;
      int bh = (bb << 4) + hh;
      if (n < 2048) {  // Q or K: [bh][t][d], scalar b16 stores
        const bool isq = n < 1024;
#pragma unroll
        for (int a = 0; a < 16; ++a) {
          int t = (mb + (a & 3) + 8 * (a >> 2)) & 2047;
          float o = acc[i][j][a] + bv;
          size_t idx = ((size_t)bh * 2048 + t) * 64 + d;
          if (isq)
            Qb[idx] = f2bf(o * 0.18033688f);
          else
            Kb[idx] = f2bf(o);
        }
      } else {  // V^T: [bh][d][t], b64 stores over reg groups
#pragma unroll
        for (int g = 0; g < 4; ++g) {
          int t = (mb + 8 * g) & 2047;
          short4v o;
#pragma unroll
          for (int r = 0; r < 4; ++r) o[r] = f2bf(acc[i][j][g * 4 + r] + bv);
          *(short4v*)&Vtb[((size_t)bh * 64 + d) * 2048 + t] = o;
        }
      }
    }
  }
}

__global__ __launch_bounds__(256, 2) void gemm_proj(
    const short* __restrict__ A, const short* __restrict__ Bt,
    const float* __restrict__ bias, float* __restrict__ out) {
  GEMM_BODY(A, Bt)
  const int rhalf = khalf * 4;
#pragma unroll
  for (int i = 0; i < 2; ++i) {
#pragma unroll
    for (int j = 0; j < 2; ++j) {
      int n = n0 + wc * 64 + j * 32 + col;
      float bv = bias[n];
      int mb = m0 + wr * 64 + i * 32 + rhalf;
#pragma unroll
      for (int a = 0; a < 16; ++a) {
        int m = mb + (a & 3) + 8 * (a >> 2);
        out[(size_t)m * 1024 + n] = acc[i][j][a] + bv;
      }
    }
  }
}

// ---------------- flash attention: barrier-free, LDS-free (R19) -------------
// One q-tile (128 rows) per block; 4 independent waves, 32 rows each.
// No __syncthreads, no LDS. K-frags b128 and V^T-frags b64 read directly
// from global (L1/L2-resident: 8KB tiles, 256KB/head; m169). Per-wave loop
// bound nkt = ((qbase+31)>>6)+1 == old block-loop + wave-uniform skip.
// Softmax (no-max exp2, pre-scaled Q), P^T-in-registers PV, and the
// epilogue are byte-identical to the R10-lineage version.
__global__ __launch_bounds__(256, 2) void flash_attn(
    const short* __restrict__ Qg_, const short* __restrict__ Kg_,
    const short* __restrict__ Vg_, short* __restrict__ Ob) {
  const int tid = threadIdx.x;
  const int wv = tid >> 6, ln = tid & 15, quad = (tid & 63) >> 4;
  const int bh = blockIdx.x & 63;
  const int qt = 15 - (blockIdx.x >> 6);  // long q-tiles dispatched first
  const short* Qg = Qg_ + (size_t)bh * 2048 * 64;
  const short* Kg = Kg_ + (size_t)bh * 2048 * 64;
  const short* Vg = Vg_ + (size_t)bh * 64 * 2048;
  const int bb = bh >> 4, hh = bh & 15;

  const int qbase = qt * 128 + wv * 32;
  const int nkt = ((qbase + 31) >> 6) + 1;

  short8 qf[2][2];
#pragma unroll
  for (int h = 0; h < 2; ++h)
#pragma unroll
    for (int ch = 0; ch < 2; ++ch)
      qf[h][ch] = *(const short8*)(Qg + (size_t)(qbase + h * 16 + ln) * 64 +
                                   ch * 32 + quad * 8);

  f32x4 Oacc[2][4];
#pragma unroll
  for (int h = 0; h < 2; ++h)
#pragma unroll
    for (int mt = 0; mt < 4; ++mt) Oacc[h][mt] = (f32x4){0.f, 0.f, 0.f, 0.f};
  float lpart[2] = {0.f, 0.f};

  for (int kt = 0; kt < nkt; ++kt) {
    const short* Kt = Kg + (size_t)kt * 64 * 64;
    const short* Vt = Vg + kt * 64;

    f32x4 St[2][4];
#pragma unroll
    for (int h = 0; h < 2; ++h)
#pragma unroll
      for (int kb = 0; kb < 4; ++kb) St[h][kb] = (f32x4){0.f, 0.f, 0.f, 0.f};
    __builtin_amdgcn_s_setprio(1);
#pragma unroll
    for (int kb = 0; kb < 4; ++kb) {
      short8 ka0 = *(const short8*)(Kt + (size_t)(kb * 16 + ln) * 64 + quad * 8);
      short8 ka1 =
          *(const short8*)(Kt + (size_t)(kb * 16 + ln) * 64 + 32 + quad * 8);
#pragma unroll
      for (int h = 0; h < 2; ++h) {
        St[h][kb] = __builtin_amdgcn_mfma_f32_16x16x32_bf16(ka0, qf[h][0],
                                                            St[h][kb], 0, 0, 0);
        St[h][kb] = __builtin_amdgcn_mfma_f32_16x16x32_bf16(ka1, qf[h][1],
                                                            St[h][kb], 0, 0, 0);
      }
    }
    __builtin_amdgcn_s_setprio(0);

    // p = exp2(s); l partials; pack. Mask only on the diagonal tile
    // (wave-uniform branch).
    short4v pf[2][4];
#pragma unroll
    for (int h = 0; h < 2; ++h) {
      float lp0 = 0.f, lp1 = 0.f;
      if (kt * 64 + 63 <= qbase + h * 16) {  // fully unmasked
#pragma unroll
        for (int kb = 0; kb < 4; ++kb) {
          float p[4];
#pragma unroll
          for (int r = 0; r < 4; ++r)
            p[r] = __builtin_amdgcn_exp2f(St[h][kb][r]);
          lp0 += p[0] + p[2];
          lp1 += p[1] + p[3];
          union { __hip_bfloat162 b2; unsigned u; } w0, w1;
          w0.b2 = __float22bfloat162_rn(make_float2(p[0], p[1]));
          w1.b2 = __float22bfloat162_rn(make_float2(p[2], p[3]));
          union { short4v s4; unsigned u2[2]; } m;
          m.u2[0] = w0.u; m.u2[1] = w1.u;
          pf[h][kb] = m.s4;
        }
      } else {  // diagonal tile: per-element causal mask
        const int qg = qbase + h * 16 + ln;
#pragma unroll
        for (int kb = 0; kb < 4; ++kb) {
          float p[4];
#pragma unroll
          for (int r = 0; r < 4; ++r) {
            int key = kt * 64 + kb * 16 + quad * 4 + r;
            float s = (key <= qg) ? St[h][kb][r] : -1e30f;
            p[r] = __builtin_amdgcn_exp2f(s);
          }
          lp0 += p[0] + p[2];
          lp1 += p[1] + p[3];
          union { __hip_bfloat162 b2; unsigned u; } w0, w1;
          w0.b2 = __float22bfloat162_rn(make_float2(p[0], p[1]));
          w1.b2 = __float22bfloat162_rn(make_float2(p[2], p[3]));
          union { short4v s4; unsigned u2[2]; } m;
          m.u2[0] = w0.u; m.u2[1] = w1.u;
          pf[h][kb] = m.s4;
        }
      }
      lpart[h] += lp0 + lp1;
    }

    __builtin_amdgcn_s_setprio(1);
#pragma unroll
    for (int kb = 0; kb < 4; ++kb)
#pragma unroll
      for (int mt = 0; mt < 4; ++mt) {
        short4v va = *(const short4v*)(Vt + (size_t)(mt * 16 + ln) * 2048 +
                                       kb * 16 + quad * 4);
#pragma unroll
        for (int h = 0; h < 2; ++h)
          Oacc[h][mt] = __builtin_amdgcn_mfma_f32_16x16x16bf16_1k(
              va, pf[h][kb], Oacc[h][mt], 0, 0, 0);
      }
    __builtin_amdgcn_s_setprio(0);
  }

#pragma unroll
  for (int h = 0; h < 2; ++h) {
    float l = lpart[h];
    l += __shfl_xor(l, 16);
    l += __shfl_xor(l, 32);
    float rl = 1.0f / l;
    int t = qbase + h * 16 + ln;
#pragma unroll
    for (int mt = 0; mt < 4; ++mt) {
      short4v o;
#pragma unroll
      for (int r = 0; r < 4; ++r) o[r] = f2bf(Oacc[h][mt][r] * rl);
      *(short4v*)(Ob + ((size_t)(bb * 2048 + t)) * 1024 + hh * 64 + mt * 16 +
                  quad * 4) = o;
    }
  }
}

// ---------------- launcher ----------------

extern "C" void kernel_launch(void* const* d_in, const int* in_sizes, int n_in,
                              void* d_out, int out_size, void* d_ws, size_t ws_size,
                              hipStream_t stream) {
  const float* x      = (const float*)d_in[0];
  const float* w_attn = (const float*)d_in[1];
  const float* b_attn = (const float*)d_in[2];
  const float* w_proj = (const float*)d_in[3];
  const float* b_proj = (const float*)d_in[4];
  float* out = (float*)d_out;
  char* ws = (char*)d_ws;

  short* xb  = (short*)(ws);
  short* wat = (short*)(ws + 16777216);
  short* wpt = (short*)(ws + 23068672);
  short* Qb  = (short*)(ws + 25165824);
  short* Kb  = (short*)(ws + 41943040);
  short* Vtb = (short*)(ws + 58720256);
  short* Ob  = (short*)(ws + 75497472);

  prep<<<12288, 256, 0, stream>>>(x, w_attn, w_proj, xb, wat, wpt);
  gemm_qkv<<<dim3(24, 64), 256, 0, stream>>>(xb, wat, b_attn, Qb, Kb, Vtb);
  flash_attn<<<1024, 256, 0, stream>>>(Qb, Kb, Vtb, Ob);
  gemm_proj<<<dim3(8, 64), 256, 0, stream>>>(Ob, wpt, b_proj, out);
}

// Round 9
// 305.282 us; speedup vs baseline: 1.3233x; 1.3233x over previous
//
#include <hip/hip_runtime.h>
#include <hip/hip_bf16.h>

// CausalSelfAttention: B=4 T=2048 C=1024 H=16 D=64
// ws layout (bytes):
//   xb   @ 0         : x as bf16           [8192][1024]   16 MB
//   wat  @ 16777216  : w_attn^T bf16       [3072][1024]    6 MB
//   wpt  @ 23068672  : w_proj^T bf16       [1024][1024]    2 MB
//   Qb   @ 25165824  : Q bf16 (pre-scaled by 0.125*log2e) [B,H,T,D] 16 MB
//   Kb   @ 41943040  : K bf16  [B,H,T,D]                  16 MB
//   V4   @ 58720256  : V fragment-tiled bf16 [bh][kt][kb][mt][lane][4] 16 MB
//   Ob   @ 75497472  : attn out bf16 [8192][1024]         16 MB
//
// R20: R19 post-mortem — barrier-free flash was right structurally (occupancy
// up, conflicts 0) but the direct V^T read was a 64-segment/instr scatter
// (8B per lane at 4KB stride) -> 219 us. Fix: gemm_qkv writes V in the EXACT
// per-fragment order flash consumes: V4[bh][kt][kb][mt][lane*4+r], so the PV
// A-operand load is V4 + frag*256 + lane*4 = one coalesced 512B segment per
// instruction. K stays direct (64B segments, R19-verified pattern). Also:
// one 32-row chunk per wave, 1024 blocks -> all 4096 waves co-resident =
// 4 waves/SIMD (2x prior flash). bid = g*64+bh keeps one bh per CU (L1
// sharing) with balanced g spread. No LDS, no barriers. GEMMs = R18.

typedef float f32x4 __attribute__((ext_vector_type(4)));
typedef float f32x16 __attribute__((ext_vector_type(16)));
typedef short short8 __attribute__((ext_vector_type(8)));
typedef short short4v __attribute__((ext_vector_type(4)));

__device__ __forceinline__ short f2bf(float f) {
  union { __hip_bfloat16 h; short s; } u;
  u.h = __float2bfloat16(f);
  return u.s;
}

__device__ __forceinline__ void gl_lds16(const void* g, void* l) {
  __builtin_amdgcn_global_load_lds(
      (const __attribute__((address_space(1))) void*)g,
      (__attribute__((address_space(3))) void*)l, 16, 0, 0);
}

// ---------------- fused prep: x cvt + w_attn^T + w_proj^T -------------------
__global__ void prep(const float* __restrict__ x, const float* __restrict__ wa,
                     const float* __restrict__ wp, short* __restrict__ xb,
                     short* __restrict__ wat, short* __restrict__ wpt) {
  const int bid = blockIdx.x, tid = threadIdx.x;
  if (bid < 8192) {
    int i = (bid * 256 + tid) * 4;
    float4 v = *(const float4*)(x + i);
    short4v o;
    o[0] = f2bf(v.x); o[1] = f2bf(v.y); o[2] = f2bf(v.z); o[3] = f2bf(v.w);
    *(short4v*)(xb + i) = o;
    return;
  }
  __shared__ float tile[32][33];
  const float* in;
  short* out;
  int N, bx, by;
  if (bid < 11264) {
    int t = bid - 8192;
    in = wa; out = wat; N = 3072; bx = t % 96; by = t / 96;
  } else {
    int t = bid - 11264;
    in = wp; out = wpt; N = 1024; bx = t & 31; by = t >> 5;
  }
  int tx = tid & 31, ty = tid >> 5;  // 32 x 8
  int x0 = bx * 32, y0 = by * 32;
#pragma unroll
  for (int i = 0; i < 32; i += 8)
    tile[ty + i][tx] = in[(size_t)(y0 + ty + i) * N + x0 + tx];
  __syncthreads();
#pragma unroll
  for (int i = 0; i < 32; i += 8)
    out[(size_t)(x0 + ty + i) * 1024 + y0 + tx] = f2bf(tile[tx][ty + i]);
}

// ------ GEMM core: 128x128, BK=32, 4 waves, DBUF LDS, 1 barrier/kt ---------
#define GEMM_BODY(A_, Bt_)                                                        \
  __shared__ __align__(16) short As[2][128 * 32];                                 \
  __shared__ __align__(16) short Bs[2][128 * 32];                                 \
  const int tid = threadIdx.x;                                                    \
  const int wv = tid >> 6;                                                        \
  const int wr = wv >> 1, wc = wv & 1;                                            \
  const int col = tid & 31, khalf = (tid >> 5) & 1;                               \
  const int m0 = blockIdx.y * 128, n0 = blockIdx.x * 128;                         \
  const int cc0 = tid, cc1 = tid + 256;                                           \
  const int row0 = cc0 >> 2, part0 = ((cc0 & 3) - ((cc0 >> 3) & 3)) & 3;          \
  const int row1 = cc1 >> 2, part1 = ((cc1 & 3) - ((cc1 >> 3) & 3)) & 3;          \
  const size_t ga0 = (size_t)(m0 + row0) * 1024 + part0 * 8;                      \
  const size_t ga1 = (size_t)(m0 + row1) * 1024 + part1 * 8;                      \
  const size_t gb0 = (size_t)(n0 + row0) * 1024 + part0 * 8;                      \
  const size_t gb1 = (size_t)(n0 + row1) * 1024 + part1 * 8;                      \
  f32x16 acc[2][2];                                                               \
  _Pragma("unroll") for (int i = 0; i < 2; ++i)                                   \
      _Pragma("unroll") for (int j = 0; j < 2; ++j)                               \
          acc[i][j] = (f32x16)(0.f);                                              \
  gl_lds16(A_ + ga0, (char*)As[0] + cc0 * 16);                                    \
  gl_lds16(A_ + ga1, (char*)As[0] + cc1 * 16);                                    \
  gl_lds16(Bt_ + gb0, (char*)Bs[0] + cc0 * 16);                                   \
  gl_lds16(Bt_ + gb1, (char*)Bs[0] + cc1 * 16);                                   \
  __syncthreads();                                                                \
  for (int kt = 0; kt < 32; ++kt) {                                               \
    if (kt + 1 < 32) {                                                            \
      const int k0 = (kt + 1) * 32;                                               \
      char* Ad = (char*)As[(kt + 1) & 1];                                         \
      char* Bd = (char*)Bs[(kt + 1) & 1];                                         \
      gl_lds16(A_ + ga0 + k0, Ad + cc0 * 16);                                     \
      gl_lds16(A_ + ga1 + k0, Ad + cc1 * 16);                                     \
      gl_lds16(Bt_ + gb0 + k0, Bd + cc0 * 16);                                    \
      gl_lds16(Bt_ + gb1 + k0, Bd + cc1 * 16);                                    \
    }                                                                             \
    const short* Ac = As[kt & 1];                                                 \
    const short* Bc = Bs[kt & 1];                                                 \
    short8 af[2][2], bf[2][2];                                                    \
    _Pragma("unroll") for (int i = 0; i < 2; ++i)                                 \
        _Pragma("unroll") for (int s = 0; s < 2; ++s) {                           \
          int pa = s * 2 + khalf;                                                 \
          int ra = wr * 64 + i * 32 + col;                                        \
          int rb = wc * 64 + i * 32 + col;                                        \
          af[i][s] = *(const short8*)&Ac[(ra * 4 + ((pa + (ra >> 1)) & 3)) * 8];  \
          bf[i][s] = *(const short8*)&Bc[(rb * 4 + ((pa + (rb >> 1)) & 3)) * 8];  \
        }                                                                         \
    _Pragma("unroll") for (int s = 0; s < 2; ++s)                                 \
        _Pragma("unroll") for (int i = 0; i < 2; ++i)                             \
            _Pragma("unroll") for (int j = 0; j < 2; ++j)                         \
                acc[i][j] = __builtin_amdgcn_mfma_f32_32x32x16_bf16(              \
                    af[i][s], bf[j][s], acc[i][j], 0, 0, 0);                      \
    __syncthreads();                                                              \
  }

// QKV GEMM. Q pre-scaled by 0.125*log2(e). V written in fragment-tiled V4
// layout: frag (bh,kt,kb,mt) is 256 contiguous shorts, lane-ordered
// (lane = quad*16 + ln, 4 shorts each) matching the PV A-operand mapping
// A[row=ln][k=quad*4+r].
__global__ __launch_bounds__(256, 2) void gemm_qkv(
    const short* __restrict__ A, const short* __restrict__ Bt,
    const float* __restrict__ bias, short* __restrict__ Qb,
    short* __restrict__ Kb, short* __restrict__ Vtb) {
  GEMM_BODY(A, Bt)
  const int rhalf = khalf * 4;
#pragma unroll
  for (int i = 0; i < 2; ++i) {
#pragma unroll
    for (int j = 0; j < 2; ++j) {
      int n = n0 + wc * 64 + j * 32 + col;
      int n2 = n & 1023;
      int hh = n2 >> 6, d = n2 & 63;
      float bv = bias[n];
      int mb = m0 + wr * 64 + i * 32 + rhalf;
      int bb = mb >> 11;
      int bh = (bb << 4) + hh;
      if (n < 2048) {  // Q or K: [bh][t][d], scalar b16 stores
        const bool isq = n < 1024;
#pragma unroll
        for (int a = 0; a < 16; ++a) {
          int t = (mb + (a & 3) + 8 * (a >> 2)) & 2047;
          float o = acc[i][j][a] + bv;
          size_t idx = ((size_t)bh * 2048 + t) * 64 + d;
          if (isq)
            Qb[idx] = f2bf(o * 0.18033688f);
          else
            Kb[idx] = f2bf(o);
        }
      } else {  // V -> V4 fragment-tiled layout
        const int lnv = d & 15, mtv = d >> 4;
#pragma unroll
        for (int g = 0; g < 4; ++g) {
          int t0 = (mb + 8 * g) & 2047;  // t0 % 4 == 0
          int ktv = t0 >> 6, kbv = (t0 >> 4) & 3, qv = (t0 >> 2) & 3;
          short4v o;
#pragma unroll
          for (int r = 0; r < 4; ++r) o[r] = f2bf(acc[i][j][g * 4 + r] + bv);
          *(short4v*)&Vtb[(size_t)(((bh * 32 + ktv) * 4 + kbv) * 4 + mtv) * 256 +
                          (qv * 16 + lnv) * 4] = o;
        }
      }
    }
  }
}

__global__ __launch_bounds__(256, 2) void gemm_proj(
    const short* __restrict__ A, const short* __restrict__ Bt,
    const float* __restrict__ bias, float* __restrict__ out) {
  GEMM_BODY(A, Bt)
  const int rhalf = khalf * 4;
#pragma unroll
  for (int i = 0; i < 2; ++i) {
#pragma unroll
    for (int j = 0; j < 2; ++j) {
      int n = n0 + wc * 64 + j * 32 + col;
      float bv = bias[n];
      int mb = m0 + wr * 64 + i * 32 + rhalf;
#pragma unroll
      for (int a = 0; a < 16; ++a) {
        int m = mb + (a & 3) + 8 * (a >> 2);
        out[(size_t)m * 1024 + n] = acc[i][j][a] + bv;
      }
    }
  }
}

// -------- flash attention: barrier-free, LDS-free, tiled-V (R20) -----------
// One 32-row chunk per wave; 1024 blocks x 4 waves = 4096 waves, all
// co-resident (16/CU = 4/SIMD). bid = g*64 + bh: one bh per CU (K/V L1
// sharing), g spread {g0,g0+4,g0+8,g0+12} balances CU load. K read direct
// from Kb (16 rows x 64B segments per b128). V read from V4: one coalesced
// 512B segment per b64 instruction. No LDS, no barriers.
__global__ __launch_bounds__(256, 4) void flash_attn(
    const short* __restrict__ Qg_, const short* __restrict__ Kg_,
    const short* __restrict__ V4_, short* __restrict__ Ob) {
  const int tid = threadIdx.x;
  const int wv = tid >> 6, ln = tid & 15, quad = (tid & 63) >> 4;
  const int lane = tid & 63;
  const int bh = blockIdx.x & 63;
  const int g = blockIdx.x >> 6;        // 0..15
  const int c = g * 4 + wv;             // chunk 0..63 (32 rows each)
  const int qbase = c * 32;
  const int nkt = ((qbase + 31) >> 6) + 1;
  const short* Qg = Qg_ + (size_t)bh * 2048 * 64;
  const short* Kg = Kg_ + (size_t)bh * 2048 * 64;
  const short* V4 = V4_ + (size_t)bh * 131072;  // 32*4*4*256
  const int bb = bh >> 4, hh = bh & 15;

  short8 qf[2][2];
#pragma unroll
  for (int h = 0; h < 2; ++h)
#pragma unroll
    for (int ch = 0; ch < 2; ++ch)
      qf[h][ch] = *(const short8*)(Qg + (size_t)(qbase + h * 16 + ln) * 64 +
                                   ch * 32 + quad * 8);

  f32x4 Oacc[2][4];
#pragma unroll
  for (int h = 0; h < 2; ++h)
#pragma unroll
    for (int mt = 0; mt < 4; ++mt) Oacc[h][mt] = (f32x4){0.f, 0.f, 0.f, 0.f};
  float lpart[2] = {0.f, 0.f};

  for (int kt = 0; kt < nkt; ++kt) {
    const short* Kt = Kg + (size_t)kt * 64 * 64;
    const short* Vt = V4 + (size_t)kt * 4096;  // 4 kb * 4 mt * 256

    f32x4 St[2][4];
#pragma unroll
    for (int h = 0; h < 2; ++h)
#pragma unroll
      for (int kb = 0; kb < 4; ++kb) St[h][kb] = (f32x4){0.f, 0.f, 0.f, 0.f};
    __builtin_amdgcn_s_setprio(1);
#pragma unroll
    for (int kb = 0; kb < 4; ++kb) {
      short8 ka0 = *(const short8*)(Kt + (size_t)(kb * 16 + ln) * 64 + quad * 8);
      short8 ka1 =
          *(const short8*)(Kt + (size_t)(kb * 16 + ln) * 64 + 32 + quad * 8);
#pragma unroll
      for (int h = 0; h < 2; ++h) {
        St[h][kb] = __builtin_amdgcn_mfma_f32_16x16x32_bf16(ka0, qf[h][0],
                                                            St[h][kb], 0, 0, 0);
        St[h][kb] = __builtin_amdgcn_mfma_f32_16x16x32_bf16(ka1, qf[h][1],
                                                            St[h][kb], 0, 0, 0);
      }
    }
    __builtin_amdgcn_s_setprio(0);

    // p = exp2(s); l partials; pack. Mask only on the diagonal tile
    // (wave-uniform branch).
    short4v pf[2][4];
#pragma unroll
    for (int h = 0; h < 2; ++h) {
      float lp0 = 0.f, lp1 = 0.f;
      if (kt * 64 + 63 <= qbase + h * 16) {  // fully unmasked
#pragma unroll
        for (int kb = 0; kb < 4; ++kb) {
          float p[4];
#pragma unroll
          for (int r = 0; r < 4; ++r)
            p[r] = __builtin_amdgcn_exp2f(St[h][kb][r]);
          lp0 += p[0] + p[2];
          lp1 += p[1] + p[3];
          union { __hip_bfloat162 b2; unsigned u; } w0, w1;
          w0.b2 = __float22bfloat162_rn(make_float2(p[0], p[1]));
          w1.b2 = __float22bfloat162_rn(make_float2(p[2], p[3]));
          union { short4v s4; unsigned u2[2]; } m;
          m.u2[0] = w0.u; m.u2[1] = w1.u;
          pf[h][kb] = m.s4;
        }
      } else {  // diagonal tile: per-element causal mask
        const int qg = qbase + h * 16 + ln;
#pragma unroll
        for (int kb = 0; kb < 4; ++kb) {
          float p[4];
#pragma unroll
          for (int r = 0; r < 4; ++r) {
            int key = kt * 64 + kb * 16 + quad * 4 + r;
            float s = (key <= qg) ? St[h][kb][r] : -1e30f;
            p[r] = __builtin_amdgcn_exp2f(s);
          }
          lp0 += p[0] + p[2];
          lp1 += p[1] + p[3];
          union { __hip_bfloat162 b2; unsigned u; } w0, w1;
          w0.b2 = __float22bfloat162_rn(make_float2(p[0], p[1]));
          w1.b2 = __float22bfloat162_rn(make_float2(p[2], p[3]));
          union { short4v s4; unsigned u2[2]; } m;
          m.u2[0] = w0.u; m.u2[1] = w1.u;
          pf[h][kb] = m.s4;
        }
      }
      lpart[h] += lp0 + lp1;
    }

    __builtin_amdgcn_s_setprio(1);
#pragma unroll
    for (int kb = 0; kb < 4; ++kb)
#pragma unroll
      for (int mt = 0; mt < 4; ++mt) {
        short4v va =
            *(const short4v*)(Vt + (kb * 4 + mt) * 256 + lane * 4);
#pragma unroll
        for (int h = 0; h < 2; ++h)
          Oacc[h][mt] = __builtin_amdgcn_mfma_f32_16x16x16bf16_1k(
              va, pf[h][kb], Oacc[h][mt], 0, 0, 0);
      }
    __builtin_amdgcn_s_setprio(0);
  }

#pragma unroll
  for (int h = 0; h < 2; ++h) {
    float l = lpart[h];
    l += __shfl_xor(l, 16);
    l += __shfl_xor(l, 32);
    float rl = 1.0f / l;
    int t = qbase + h * 16 + ln;
#pragma unroll
    for (int mt = 0; mt < 4; ++mt) {
      short4v o;
#pragma unroll
      for (int r = 0; r < 4; ++r) o[r] = f2bf(Oacc[h][mt][r] * rl);
      *(short4v*)(Ob + ((size_t)(bb * 2048 + t)) * 1024 + hh * 64 + mt * 16 +
                  quad * 4) = o;
    }
  }
}

// ---------------- launcher ----------------

extern "C" void kernel_launch(void* const* d_in, const int* in_sizes, int n_in,
                              void* d_out, int out_size, void* d_ws, size_t ws_size,
                              hipStream_t stream) {
  const float* x      = (const float*)d_in[0];
  const float* w_attn = (const float*)d_in[1];
  const float* b_attn = (const float*)d_in[2];
  const float* w_proj = (const float*)d_in[3];
  const float* b_proj = (const float*)d_in[4];
  float* out = (float*)d_out;
  char* ws = (char*)d_ws;

  short* xb  = (short*)(ws);
  short* wat = (short*)(ws + 16777216);
  short* wpt = (short*)(ws + 23068672);
  short* Qb  = (short*)(ws + 25165824);
  short* Kb  = (short*)(ws + 41943040);
  short* Vtb = (short*)(ws + 58720256);
  short* Ob  = (short*)(ws + 75497472);

  prep<<<12288, 256, 0, stream>>>(x, w_attn, w_proj, xb, wat, wpt);
  gemm_qkv<<<dim3(24, 64), 256, 0, stream>>>(xb, wat, b_attn, Qb, Kb, Vtb);
  flash_attn<<<1024, 256, 0, stream>>>(Qb, Kb, Vtb, Ob);
  gemm_proj<<<dim3(8, 64), 256, 0, stream>>>(Ob, wpt, b_proj, out);
}